// Round 1
// baseline (124.640 us; speedup 1.0000x reference)
//
#include <hip/hip_runtime.h>
#include <math.h>

// BayesianSkipgram: V=100000, E=256, D=128, B=8192, C=10
// Fused single kernel: gathered-GEMM (emb @ M_w^T) -> relu-sum -> GEMM
// (h @ [U_w;W_w]^T) -> softplus -> closed-form KL.  fp32 vector math.

#define BT    16          // batch elements per block
#define SLOTS 11          // C+1 (slot 0 = x, slots 1..10 = context)
#define ROWS  (BT*SLOTS)  // 176 gathered rows per block
#define EDIM  256
#define DDIM  128
#define CTXN  10
#define EK    32          // K-chunk staged in LDS
#define LP    33          // padded LDS row stride (floats)

// shared-memory float offsets (regions overlap across phases; see barriers)
#define OFF_A   176            // phase1 A tile: 176*33 = 5808  -> ends 5984
#define OFF_M   5984           // phase1 M tile: 128*33 = 4224  -> ends 10208
#define OFF_H   176            // phase2 h tile: 16*257 = 4112  -> ends 4288
#define OFF_UW  4288           // phase2 weights: 256*33 = 8448 -> ends 12736
#define OFF_P   12736          // kl partials: 64              -> ends 12800
#define SMEM_F  12800          // 51200 bytes

__device__ __forceinline__ float softplusf(float v) {
    return fmaxf(v, 0.0f) + log1pf(expf(-fabsf(v)));
}

__global__ __launch_bounds__(256, 2) void bsg_fused(
    const int*   __restrict__ x,     const int*   __restrict__ ctx,
    const float* __restrict__ W_emb, const float* __restrict__ M_w,
    const float* __restrict__ M_b,   const float* __restrict__ U_w,
    const float* __restrict__ U_b,   const float* __restrict__ W_w,
    const float* __restrict__ W_b,   const float* __restrict__ pmu,
    const float* __restrict__ psg,   float* __restrict__ out)
{
    __shared__ float smem[SMEM_F];
    int*   idx_s = (int*)smem;          // 176 ints, persists whole kernel
    float* A_s   = smem + OFF_A;
    float* M_s   = smem + OFF_M;
    float* H_s   = smem + OFF_H;
    float* UW_s  = smem + OFF_UW;
    float* P_s   = smem + OFF_P;

    const int tid = threadIdx.x;
    const int b0  = blockIdx.x * BT;

    // gather indices once: row r = 11*b_local + c ; c==0 -> x, else context
    if (tid < ROWS) {
        int bl = tid / SLOTS, c = tid - bl * SLOTS;
        int b  = b0 + bl;
        idx_s[tid] = (c == 0) ? x[b] : ctx[b * CTXN + (c - 1)];
    }
    __syncthreads();

    // ---------------- phase 1: Rall = gathered_emb @ M_w^T ----------------
    // thread (i,j): i = batch-local element (owns all 11 slots), j = col group
    const int i = tid & 15;
    const int j = tid >> 4;
    float acc[SLOTS][8];
#pragma unroll
    for (int c = 0; c < SLOTS; ++c)
#pragma unroll
        for (int m = 0; m < 8; ++m) acc[c][m] = 0.0f;

    for (int ch = 0; ch < EDIM / EK; ++ch) {
        const int e0 = ch * EK;
        // stage gathered A rows: 176 rows x 32 floats (8 float4 each)
        for (int it = tid; it < ROWS * 8; it += 256) {
            int r = it >> 3, q = it & 7;
            float4 v = ((const float4*)W_emb)[(size_t)idx_s[r] * 64 + (e0 >> 2) + q];
            float* dst = &A_s[r * LP + 4 * q];
            dst[0] = v.x; dst[1] = v.y; dst[2] = v.z; dst[3] = v.w;
        }
        // stage M_w chunk: 128 rows x 32 floats
        for (int it = tid; it < DDIM * 8; it += 256) {
            int d = it >> 3, q = it & 7;
            float4 v = ((const float4*)M_w)[d * 64 + (e0 >> 2) + q];
            float* dst = &M_s[d * LP + 4 * q];
            dst[0] = v.x; dst[1] = v.y; dst[2] = v.z; dst[3] = v.w;
        }
        __syncthreads();
#pragma unroll 4
        for (int e = 0; e < EK; ++e) {
            float mf[8];
#pragma unroll
            for (int m = 0; m < 8; ++m) mf[m] = M_s[(j + 16 * m) * LP + e];
#pragma unroll
            for (int c = 0; c < SLOTS; ++c) {
                float av = A_s[(SLOTS * i + c) * LP + e];
#pragma unroll
                for (int m = 0; m < 8; ++m)
                    acc[c][m] = fmaf(av, mf[m], acc[c][m]);
            }
        }
        __syncthreads();
    }

    // relu-sum epilogue (register-local per batch element)
    {
        float h1[8], h2[8];
#pragma unroll
        for (int m = 0; m < 8; ++m) {
            float mb = M_b[j + 16 * m];
            float rw = acc[0][m] + mb;
            h1[m] = 10.0f * fmaxf(rw, 0.0f);     // C * relu(Rw)
            float s = 0.0f;
#pragma unroll
            for (int c = 1; c < SLOTS; ++c) s += fmaxf(acc[c][m] + mb, 0.0f);
            h2[m] = s;                            // sum_c relu(Rc)
        }
#pragma unroll
        for (int m = 0; m < 8; ++m) {
            H_s[i * 257 + (j + 16 * m)]       = h1[m];
            H_s[i * 257 + 128 + (j + 16 * m)] = h2[m];
        }
    }

    // ---------------- phase 2: [mu|presig] = h @ [U_w;W_w]^T ----------------
    const int bi = tid & 3;            // batch sub-group
    const int nj = (tid >> 2) & 63;    // col sub-group (global, spans waves)
    const int wv = tid >> 6;           // wave id
    float acc2[4][4];
#pragma unroll
    for (int bb = 0; bb < 4; ++bb)
#pragma unroll
        for (int mm = 0; mm < 4; ++mm) acc2[bb][mm] = 0.0f;

    for (int ch = 0; ch < 2 * DDIM / EK; ++ch) {
        const int e0 = ch * EK;
        // stage [U_w;W_w] chunk: 256 rows x 32 floats
        for (int it = tid; it < 256 * 8; it += 256) {
            int n = it >> 3, q = it & 7;
            const float* src = (n < DDIM) ? U_w : W_w;
            float4 v = ((const float4*)src)[(n & 127) * 64 + (e0 >> 2) + q];
            float* dst = &UW_s[n * LP + 4 * q];
            dst[0] = v.x; dst[1] = v.y; dst[2] = v.z; dst[3] = v.w;
        }
        __syncthreads();
#pragma unroll 4
        for (int e = 0; e < EK; ++e) {
            float hv[4], wf[4];
#pragma unroll
            for (int bb = 0; bb < 4; ++bb)
                hv[bb] = H_s[(bi + 4 * bb) * 257 + e0 + e];
#pragma unroll
            for (int mm = 0; mm < 4; ++mm)
                wf[mm] = UW_s[(nj + 64 * mm) * LP + e];
#pragma unroll
            for (int bb = 0; bb < 4; ++bb)
#pragma unroll
                for (int mm = 0; mm < 4; ++mm)
                    acc2[bb][mm] = fmaf(hv[bb], wf[mm], acc2[bb][mm]);
        }
        __syncthreads();
    }

    // ---------------- epilogue: bias, softplus, KL ----------------
    // thread's cols: n = nj + 64*mm. mm=0,1 -> mu(d=nj, nj+64); mm=2,3 -> sigma(same d)
#pragma unroll
    for (int mm = 0; mm < 4; ++mm) {
        int n = nj + 64 * mm;
        float bias = (n < DDIM) ? U_b[n] : W_b[n - DDIM];
#pragma unroll
        for (int bb = 0; bb < 4; ++bb) acc2[bb][mm] += bias;
    }

#pragma unroll
    for (int bb = 0; bb < 4; ++bb) {
        int b  = bi + 4 * bb;
        int xb = idx_s[SLOTS * b];       // = x[b0 + b]
        float p = 0.0f;
#pragma unroll
        for (int t = 0; t < 2; ++t) {
            int   d  = nj + 64 * t;
            float mu = acc2[bb][t];
            float sg = softplusf(acc2[bb][2 + t]);
            float m0 = pmu[(size_t)xb * DDIM + d];
            float s0 = psg[(size_t)xb * DDIM + d];
            float dm = mu - m0;
            p += s0 / sg + dm * dm / sg + logf(sg) - logf(s0);
        }
        // butterfly-sum over the 16 nj-lanes within the wave (lane = bi + 4*nj_loc)
        p += __shfl_xor(p, 4);
        p += __shfl_xor(p, 8);
        p += __shfl_xor(p, 16);
        p += __shfl_xor(p, 32);
        if ((tid & 63) < 4) P_s[b * 4 + wv] = p;   // lanes 0..3 hold bi=lane sums
    }
    __syncthreads();
    if (tid < BT) {
        float s = P_s[tid * 4 + 0] + P_s[tid * 4 + 1]
                + P_s[tid * 4 + 2] + P_s[tid * 4 + 3];
        out[b0 + tid] = 0.5f * (s - (float)DDIM);
    }
}

extern "C" void kernel_launch(void* const* d_in, const int* in_sizes, int n_in,
                              void* d_out, int out_size, void* d_ws, size_t ws_size,
                              hipStream_t stream) {
    const int*   x     = (const int*)  d_in[0];
    const int*   ctx   = (const int*)  d_in[1];
    const float* W_emb = (const float*)d_in[2];
    const float* M_w   = (const float*)d_in[3];
    const float* M_b   = (const float*)d_in[4];
    const float* U_w   = (const float*)d_in[5];
    const float* U_b   = (const float*)d_in[6];
    const float* W_w   = (const float*)d_in[7];
    const float* W_b   = (const float*)d_in[8];
    const float* pmu   = (const float*)d_in[9];
    const float* psg   = (const float*)d_in[10];
    float* out = (float*)d_out;

    bsg_fused<<<dim3(8192 / BT), dim3(256), 0, stream>>>(
        x, ctx, W_emb, M_w, M_b, U_w, U_b, W_w, W_b, pmu, psg, out);
}

// Round 2
// 52.036 us; speedup vs baseline: 2.3953x; 2.3953x over previous
//
#include <hip/hip_runtime.h>
#include <hip/hip_bf16.h>
#include <math.h>

// BayesianSkipgram: V=100000, E=256, D=128, B=8192, C=10
// bf16-MFMA fused kernel:
//   phase 1: Rall[176,128] = gathered_emb @ M_w^T   (16x16x32 bf16 MFMA)
//   relu-sum -> h[16,256] (register-local per wave, slot-major row layout)
//   phase 2: [mu|presig][16,256] = h @ [U_w;W_w]^T  (MFMA)
//   epilogue: softplus, closed-form KL, register-local reduce.

#define BT    16
#define SLOTS 11
#define ROWS  176          // BT*SLOTS, row r = c*16 + b (slot-major)
#define EDIM  256
#define DDIM  128
#define CTXN  10
#define EK    64           // K chunk per staging round
#define LP    72           // LDS row stride (bf16 elems): 64 + 8 pad -> 2-way bank alias (free)
#define HLP   264          // h LDS row stride: 256 + 8 pad

typedef short  bf16x8 __attribute__((ext_vector_type(8)));
typedef float  f32x4  __attribute__((ext_vector_type(4)));

// LDS (ushort elems): phase1 A=[176][72] @0 (12672), M=[128][72] @12672 (9216) -> 21888
//                     phase2 H=[16][264] @0 (4224), UW=[256][72] @4224 (18432) -> 22656
#define OFF_M  12672
#define OFF_UW 4224
#define SMEM_U 22656

__device__ __forceinline__ uint2 cvt4(float4 v) {
    union { __hip_bfloat162 h2; unsigned u; } a, b;
    a.h2 = __float22bfloat162_rn(make_float2(v.x, v.y));
    b.h2 = __float22bfloat162_rn(make_float2(v.z, v.w));
    return make_uint2(a.u, b.u);
}

__device__ __forceinline__ float softplusf(float v) {
    return fmaxf(v, 0.0f) + log1pf(expf(-fabsf(v)));
}

__global__ __launch_bounds__(256, 3) void bsg_mfma(
    const int*   __restrict__ x,     const int*   __restrict__ ctx,
    const float* __restrict__ W_emb, const float* __restrict__ M_w,
    const float* __restrict__ M_b,   const float* __restrict__ U_w,
    const float* __restrict__ U_b,   const float* __restrict__ W_w,
    const float* __restrict__ W_b,   const float* __restrict__ pmu,
    const float* __restrict__ psg,   float* __restrict__ out)
{
    __shared__ unsigned short sm[SMEM_U];
    __shared__ int   idx_s[ROWS];
    __shared__ float P_s[BT * 4];

    unsigned short* A_s  = sm;
    unsigned short* M_s  = sm + OFF_M;
    unsigned short* H_s  = sm;
    unsigned short* UW_s = sm + OFF_UW;

    const int tid  = threadIdx.x;
    const int b0   = blockIdx.x * BT;
    const int w    = tid >> 6;        // wave 0..3
    const int lane = tid & 63;
    const int l15  = lane & 15;
    const int lg   = lane >> 4;       // 0..3

    // gather indices: row r = c*16 + b  (c==0 -> x, else context[c-1])
    if (tid < ROWS) {
        int c = tid >> 4, b = b0 + (tid & 15);
        idx_s[tid] = (c == 0) ? x[b] : ctx[b * CTXN + (c - 1)];
    }
    __syncthreads();

    // ---------------- phase 1: Rall = gathered_emb @ M_w^T ----------------
    // wave w owns N-tiles {2w, 2w+1} (cols d = 32w..32w+31), all 11 slots.
    f32x4 acc[SLOTS][2] = {};

    for (int ch = 0; ch < EDIM / EK; ++ch) {
        const int k0 = ch * EK;
        // stage gathered A rows (176 x 64 fp32 -> bf16)
        for (int it = tid; it < ROWS * 16; it += 256) {
            int r = it >> 4, q = it & 15;
            float4 v = ((const float4*)W_emb)[(size_t)idx_s[r] * 64 + (k0 >> 2) + q];
            *(uint2*)&A_s[r * LP + 4 * q] = cvt4(v);
        }
        // stage M_w chunk (128 x 64)
        for (int it = tid; it < DDIM * 16; it += 256) {
            int d = it >> 4, q = it & 15;
            float4 v = ((const float4*)M_w)[d * 64 + (k0 >> 2) + q];
            *(uint2*)&M_s[d * LP + 4 * q] = cvt4(v);
        }
        __syncthreads();

        bf16x8 bfr[2][2];
#pragma unroll
        for (int nt2 = 0; nt2 < 2; ++nt2)
#pragma unroll
            for (int kh = 0; kh < 2; ++kh)
                bfr[nt2][kh] = *(const bf16x8*)&M_s[(16 * (2 * w + nt2) + l15) * LP + 32 * kh + 8 * lg];

#pragma unroll
        for (int c = 0; c < SLOTS; ++c) {
            bf16x8 a0 = *(const bf16x8*)&A_s[(16 * c + l15) * LP + 8 * lg];
            bf16x8 a1 = *(const bf16x8*)&A_s[(16 * c + l15) * LP + 32 + 8 * lg];
            acc[c][0] = __builtin_amdgcn_mfma_f32_16x16x32_bf16(a0, bfr[0][0], acc[c][0], 0, 0, 0);
            acc[c][0] = __builtin_amdgcn_mfma_f32_16x16x32_bf16(a1, bfr[0][1], acc[c][0], 0, 0, 0);
            acc[c][1] = __builtin_amdgcn_mfma_f32_16x16x32_bf16(a0, bfr[1][0], acc[c][1], 0, 0, 0);
            acc[c][1] = __builtin_amdgcn_mfma_f32_16x16x32_bf16(a1, bfr[1][1], acc[c][1], 0, 0, 0);
        }
        __syncthreads();
    }

    // relu-sum epilogue -> h (bf16, LDS).  D-layout: col=lane&15, row=lg*4+q.
#pragma unroll
    for (int nt2 = 0; nt2 < 2; ++nt2) {
        int dg = 16 * (2 * w + nt2) + l15;       // global d, 0..127
        float mb = M_b[dg];
#pragma unroll
        for (int q = 0; q < 4; ++q) {
            int m = lg * 4 + q;
            float h1 = 10.0f * fmaxf(acc[0][nt2][q] + mb, 0.0f);
            float h2 = 0.0f;
#pragma unroll
            for (int c = 1; c < SLOTS; ++c) h2 += fmaxf(acc[c][nt2][q] + mb, 0.0f);
            __hip_bfloat16 t1 = __float2bfloat16(h1);
            __hip_bfloat16 t2 = __float2bfloat16(h2);
            H_s[m * HLP + dg]        = *(unsigned short*)&t1;
            H_s[m * HLP + 128 + dg]  = *(unsigned short*)&t2;
        }
    }
    __syncthreads();

    // ---------------- phase 2: [mu|presig] = h @ [U_w;W_w]^T ----------------
    // wave w owns N-tiles {2w, 2w+1, 2w+8, 2w+9}: mu cols 32w..32w+31 and the
    // matching presig cols 128+32w.. -> KL epilogue is register-local.
    f32x4 acc2[4] = {};

    for (int ch = 0; ch < 2 * DDIM / EK; ++ch) {
        const int k0 = ch * EK;
        for (int it = tid; it < 256 * 16; it += 256) {
            int n = it >> 4, q = it & 15;
            float4 v = ((const float4*)(n < DDIM ? U_w : W_w))[(n & 127) * 64 + (k0 >> 2) + q];
            *(uint2*)&UW_s[n * LP + 4 * q] = cvt4(v);
        }
        __syncthreads();

        bf16x8 haf[2];
#pragma unroll
        for (int kh = 0; kh < 2; ++kh)
            haf[kh] = *(const bf16x8*)&H_s[l15 * HLP + k0 + 32 * kh + 8 * lg];
#pragma unroll
        for (int ntl = 0; ntl < 4; ++ntl) {
            int ntg = 2 * w + (ntl & 1) + 8 * (ntl >> 1);
#pragma unroll
            for (int kh = 0; kh < 2; ++kh) {
                bf16x8 bfrag = *(const bf16x8*)&UW_s[(16 * ntg + l15) * LP + 32 * kh + 8 * lg];
                acc2[ntl] = __builtin_amdgcn_mfma_f32_16x16x32_bf16(haf[kh], bfrag, acc2[ntl], 0, 0, 0);
            }
        }
        __syncthreads();
    }

    // ---------------- epilogue: bias, softplus, KL ----------------
    // lane holds mu at acc2[0..1] (d = 16*(2w+t)+l15), presig at acc2[2..3] (same d)
    float ub[2], wb[2];
#pragma unroll
    for (int t = 0; t < 2; ++t) {
        int d = 16 * (2 * w + t) + l15;
        ub[t] = U_b[d];
        wb[t] = W_b[d];
    }
#pragma unroll
    for (int q = 0; q < 4; ++q) {
        int m  = lg * 4 + q;
        int xb = idx_s[m];               // = x[b0 + m]  (slot 0 row)
        float p = 0.0f;
#pragma unroll
        for (int t = 0; t < 2; ++t) {
            int   d  = 16 * (2 * w + t) + l15;
            float mu = acc2[t][q] + ub[t];
            float sg = softplusf(acc2[2 + t][q] + wb[t]);
            float m0 = pmu[(size_t)xb * DDIM + d];
            float s0 = psg[(size_t)xb * DDIM + d];
            float dm = mu - m0;
            p += s0 / sg + dm * dm / sg + logf(sg) - logf(s0);
        }
        // sum over the 16 lanes of this lane-group (covers this wave's 32 d's)
        p += __shfl_xor(p, 1);
        p += __shfl_xor(p, 2);
        p += __shfl_xor(p, 4);
        p += __shfl_xor(p, 8);
        if (l15 == 0) P_s[m * 4 + w] = p;
    }
    __syncthreads();
    if (tid < BT) {
        float s = P_s[tid * 4 + 0] + P_s[tid * 4 + 1]
                + P_s[tid * 4 + 2] + P_s[tid * 4 + 3];
        out[b0 + tid] = 0.5f * (s - (float)DDIM);
    }
}

extern "C" void kernel_launch(void* const* d_in, const int* in_sizes, int n_in,
                              void* d_out, int out_size, void* d_ws, size_t ws_size,
                              hipStream_t stream) {
    const int*   x     = (const int*)  d_in[0];
    const int*   ctx   = (const int*)  d_in[1];
    const float* W_emb = (const float*)d_in[2];
    const float* M_w   = (const float*)d_in[3];
    const float* M_b   = (const float*)d_in[4];
    const float* U_w   = (const float*)d_in[5];
    const float* U_b   = (const float*)d_in[6];
    const float* W_w   = (const float*)d_in[7];
    const float* W_b   = (const float*)d_in[8];
    const float* pmu   = (const float*)d_in[9];
    const float* psg   = (const float*)d_in[10];
    float* out = (float*)d_out;

    bsg_mfma<<<dim3(8192 / BT), dim3(256), 0, stream>>>(
        x, ctx, W_emb, M_w, M_b, U_w, U_b, W_w, W_b, pmu, psg, out);
}